// Round 1
// baseline (848.647 us; speedup 1.0000x reference)
//
#include <hip/hip_runtime.h>

#define ROWLEN 16384
#define NF4 (ROWLEN / 4)          // 4096 float4 per row
#define KSEL 64u

// Order-preserving float -> u32 key (larger key == larger float, NaN-free input)
__device__ __forceinline__ unsigned f2k(float f) {
    unsigned u = __float_as_uint(f);
    return (u & 0x80000000u) ? ~u : (u | 0x80000000u);
}
__device__ __forceinline__ float k2f(unsigned k) {
    unsigned u = (k & 0x80000000u) ? (k ^ 0x80000000u) : ~k;
    return __uint_as_float(u);
}

__global__ __launch_bounds__(256, 4)
void sparsify_topk_kernel(const float* __restrict__ x, float* __restrict__ out, int rows) {
    const int t = threadIdx.x;
    const int row = blockIdx.x;
    if (row >= rows) return;  // uniform per block

    __shared__ unsigned hist[256];
    __shared__ unsigned selBin, selK;

    // ---- Load row into registers as sortable keys (coalesced float4) ----
    const float4* xrow = (const float4*)(x + (size_t)row * ROWLEN);
    unsigned keys[64];
#pragma unroll
    for (int j = 0; j < 16; ++j) {
        float4 v = xrow[j * 256 + t];
        keys[4 * j + 0] = f2k(v.x);
        keys[4 * j + 1] = f2k(v.y);
        keys[4 * j + 2] = f2k(v.z);
        keys[4 * j + 3] = f2k(v.w);
    }

    unsigned prefix = 0;   // key bits above current pass (block-uniform)
    unsigned kcur = KSEL;  // remaining rank within prefix (block-uniform, <= 64)

    // Exact radix-select pass: histogram 8 bits at SHIFT among prefix-matching
    // keys with saturating counts (cap 64 == K; exactness below the cap is all
    // the suffix-scan selection needs), then pick the bin holding rank kcur.
#define HPASS(SHIFT, FIRST)                                                    \
    {                                                                          \
        hist[t] = 0;                                                           \
        __syncthreads();                                                       \
        _Pragma("unroll")                                                      \
        for (int e = 0; e < 64; ++e) {                                         \
            unsigned key = keys[e];                                            \
            bool valid = (FIRST) || ((key >> ((SHIFT) + 8)) == prefix);        \
            if (valid) {                                                       \
                unsigned b = (key >> (SHIFT)) & 255u;                          \
                if (hist[b] < KSEL) atomicAdd(&hist[b], 1u);                   \
            }                                                                  \
        }                                                                      \
        __syncthreads();                                                       \
        if (t < 64) {                                                          \
            unsigned c0 = hist[4 * t + 0], c1 = hist[4 * t + 1];               \
            unsigned c2 = hist[4 * t + 2], c3 = hist[4 * t + 3];               \
            unsigned s = c0 + c1 + c2 + c3;                                    \
            _Pragma("unroll")                                                  \
            for (int d = 1; d < 64; d <<= 1) {                                 \
                unsigned v = __shfl_down(s, d);                                \
                if (t + d < 64) s += v;                                        \
            }                                                                  \
            unsigned sAb = __shfl_down(s, 1);                                  \
            if (t == 63) sAb = 0;                                              \
            if (s >= kcur && sAb < kcur) { /* exactly one lane */              \
                unsigned a = sAb;                                              \
                int bin; unsigned kn;                                          \
                if (a + c3 >= kcur)                { bin = 4*t+3; kn = kcur - a; }                    \
                else if (a + c3 + c2 >= kcur)      { bin = 4*t+2; kn = kcur - a - c3; }               \
                else if (a + c3 + c2 + c1 >= kcur) { bin = 4*t+1; kn = kcur - a - c3 - c2; }          \
                else                               { bin = 4*t+0; kn = kcur - a - c3 - c2 - c1; }     \
                selBin = (unsigned)bin;                                        \
                selK = kn;                                                     \
            }                                                                  \
        }                                                                      \
        __syncthreads();                                                       \
        prefix = (prefix << 8) | selBin;                                       \
        kcur = selK;                                                           \
    }

    HPASS(24, true)
    HPASS(16, false)
    HPASS(8, false)
    HPASS(0, false)
#undef HPASS

    const unsigned tkey = prefix;  // exact key of the K-th largest value

    // ---- Epilogue: mask in key space, reconstruct floats, coalesced store ----
    float4* orow = (float4*)out + (size_t)row * NF4;
#pragma unroll
    for (int j = 0; j < 16; ++j) {
        unsigned k0 = keys[4 * j + 0], k1 = keys[4 * j + 1];
        unsigned k2 = keys[4 * j + 2], k3 = keys[4 * j + 3];
        float4 o;
        o.x = (k0 >= tkey) ? k2f(k0) : 0.0f;
        o.y = (k1 >= tkey) ? k2f(k1) : 0.0f;
        o.z = (k2 >= tkey) ? k2f(k2) : 0.0f;
        o.w = (k3 >= tkey) ? k2f(k3) : 0.0f;
        orow[j * 256 + t] = o;
    }
}

extern "C" void kernel_launch(void* const* d_in, const int* in_sizes, int n_in,
                              void* d_out, int out_size, void* d_ws, size_t ws_size,
                              hipStream_t stream) {
    const float* x = (const float*)d_in[0];
    float* out = (float*)d_out;
    const int rows = in_sizes[0] / ROWLEN;
    sparsify_topk_kernel<<<rows, 256, 0, stream>>>(x, out, rows);
}